// Round 10
// baseline (188.804 us; speedup 1.0000x reference)
//
#include <hip/hip_runtime.h>

typedef __attribute__((ext_vector_type(8))) _Float16 h8;
typedef __attribute__((ext_vector_type(4))) _Float16 h4;
typedef __attribute__((ext_vector_type(4))) float f4;
typedef __attribute__((ext_vector_type(16))) float f16x;
typedef __attribute__((ext_vector_type(4))) unsigned u4;

#define MFMA16(a,b,c) __builtin_amdgcn_mfma_f32_16x16x32_f16(a,b,c,0,0,0)
#define MFMA32(a,b,c) __builtin_amdgcn_mfma_f32_32x32x16_f16(a,b,c,0,0,0)

// async global->LDS, 16B per lane; LDS dest = wave-uniform base + lane*16
__device__ inline void gload16(const void* g, void* l) {
    __builtin_amdgcn_global_load_lds(
        (const __attribute__((address_space(1))) void*)g,
        (__attribute__((address_space(3))) void*)l, 16, 0, 0);
}

// partner-half (lane ^ 32) value, semantics-guaranteed
__device__ inline float swap_half(float x) { return __shfl_xor(x, 32, 64); }

// ---------------- fp32 -> f16 elementwise (vectorized) ----------------
__global__ __launch_bounds__(256) void k_f32_to_f16(const float* __restrict__ in,
                                                    _Float16* __restrict__ out, int n4) {
    int i = blockIdx.x * 256 + threadIdx.x;
    if (i < n4) {
        float4 v = ((const float4*)in)[i];
        h4 h;
        h[0] = (_Float16)v.x; h[1] = (_Float16)v.y;
        h[2] = (_Float16)v.z; h[3] = (_Float16)v.w;
        ((h4*)out)[i] = h;
    }
}

// ---------------- fp32 (K,N) -> f16 (N,K) tiled transpose ----------------
__global__ __launch_bounds__(256) void k_transpose_f16(const float* __restrict__ W,
                                                       _Float16* __restrict__ Wt,
                                                       int K, int N) {
    __shared__ float tile[64 * 68];
    const int k0 = blockIdx.x * 64, n0 = blockIdx.y * 64;
    const int t = threadIdx.x;
    const int tr = t >> 4;
    const int tc = t & 15;
#pragma unroll
    for (int i = 0; i < 4; ++i) {
        int r = tr + i * 16;
        float4 v = *(const float4*)(W + (size_t)(k0 + r) * N + n0 + tc * 4);
        *(float4*)(&tile[r * 68 + tc * 4]) = v;
    }
    __syncthreads();
#pragma unroll
    for (int i = 0; i < 4; ++i) {
        int nl = tr + i * 16;
        h4 hv;
#pragma unroll
        for (int j = 0; j < 4; ++j)
            hv[j] = (_Float16)tile[(tc * 4 + j) * 68 + nl];
        *(h4*)(Wt + (size_t)(n0 + nl) * K + k0 + tc * 4) = hv;
    }
}

// ======== 256x256 x BK=64 8-phase GEMM (QKV): 8 waves, 32x32x16 MFMA, T2+T4+T5 ========
// Slot s holds A[256][64] + B[256][64] (f16, linear rows for global_load_lds).
// T2 swizzle: LDS (row, segL) holds global seg segL ^ (row&7); applied on per-lane
// SOURCE address at stage time and on frag-read addresses (involution).
// Iteration t: 4 phases (phase p = k-slice p: 6 ds_read_b128 + 8 MFMA between raw
// barriers); phases 0/1 stage tile t+1 into slot s^1 (its readers finished last
// iteration -> race-free by construction); vmcnt(0) at phase 3 (~2 phases of cover).
__global__ __launch_bounds__(512, 2) void k_gemm256(const _Float16* __restrict__ A,
                                                    const _Float16* __restrict__ Bt,
                                                    const float* __restrict__ bias,
                                                    _Float16* __restrict__ oQ,
                                                    _Float16* __restrict__ oK,
                                                    _Float16* __restrict__ oV,
                                                    int K, int nbn) {
    __shared__ _Float16 As[2][256 * 64];
    __shared__ _Float16 Bs[2][256 * 64];
    const int nwg = gridDim.x;
    const int q8 = nwg >> 3;                       // nwg % 8 == 0
    const int wg = (blockIdx.x & 7) * q8 + (blockIdx.x >> 3);   // XCD-chunked, bijective
    const int bm = (wg / nbn) * 256, bn = (wg % nbn) * 256;
    const int tid = threadIdx.x, lane = tid & 63, wv = tid >> 6;
    const int wm = wv >> 2, wn = wv & 3;           // 2 x 4 waves -> 128 x 64 per wave
    const int l31 = lane & 31, hi = lane >> 5;
    const int srow = lane >> 3;                    // staging row-in-octet 0..7
    const int scol = ((lane & 7) ^ srow) * 8;      // T2: pre-swizzled source col
    const _Float16* Ag = A + (size_t)(bm + wv * 8 + srow) * K + scol;
    const _Float16* Bg = Bt + (size_t)(bn + wv * 8 + srow) * K + scol;
    f16x acc[4][2] = {};

    // prologue: tile 0 -> slot 0
#pragma unroll
    for (int j = 0; j < 4; ++j) gload16(Ag + (size_t)j * 64 * K, &As[0][(j * 64 + wv * 8) * 64]);
#pragma unroll
    for (int j = 0; j < 4; ++j) gload16(Bg + (size_t)j * 64 * K, &Bs[0][(j * 64 + wv * 8) * 64]);
    asm volatile("s_waitcnt vmcnt(0)" ::: "memory");
    __builtin_amdgcn_s_barrier();

    const int NT = K >> 6;
    int s = 0;
    for (int t = 0; t < NT; ++t) {
        const bool pre = (t + 1 < NT);
        const size_t ko = (size_t)(t + 1) << 6;
#pragma unroll
        for (int p = 0; p < 4; ++p) {
            // ds reads for k-slice p (k = p*16 + hi*8 + e)
            const int segA = ((p * 2 + hi) ^ (l31 & 7)) * 8;
            h8 af[4], bf[2];
#pragma unroll
            for (int mf = 0; mf < 4; ++mf)
                af[mf] = *(const h8*)(&As[s][(wm * 128 + mf * 32 + l31) * 64 + segA]);
#pragma unroll
            for (int nf = 0; nf < 2; ++nf)
                bf[nf] = *(const h8*)(&Bs[s][(wn * 64 + nf * 32 + l31) * 64 + segA]);
            if (pre) {
                if (p == 0) {
#pragma unroll
                    for (int j = 0; j < 4; ++j)
                        gload16(Ag + (size_t)j * 64 * K + ko, &As[s ^ 1][(j * 64 + wv * 8) * 64]);
                } else if (p == 1) {
#pragma unroll
                    for (int j = 0; j < 4; ++j)
                        gload16(Bg + (size_t)j * 64 * K + ko, &Bs[s ^ 1][(j * 64 + wv * 8) * 64]);
                } else if (p == 3) {
                    asm volatile("s_waitcnt vmcnt(0)" ::: "memory");  // tile t+1 resident
                }
            }
            __builtin_amdgcn_s_barrier();
            __builtin_amdgcn_s_setprio(1);
#pragma unroll
            for (int mf = 0; mf < 4; ++mf)
#pragma unroll
                for (int nf = 0; nf < 2; ++nf)
                    acc[mf][nf] = MFMA32(af[mf], bf[nf], acc[mf][nf]);
            __builtin_amdgcn_s_setprio(0);
            __builtin_amdgcn_s_barrier();
        }
        s ^= 1;
    }

    // epilogue: scatter into Q/K (B,H,T,64) and V^T (B,H,64,T); Q pre-scaled
#pragma unroll
    for (int mf = 0; mf < 4; ++mf) {
#pragma unroll
        for (int nf = 0; nf < 2; ++nf) {
            const int col = bn + wn * 64 + nf * 32 + l31;
            const float bv = bias[col];
            const int which = col >> 10;
            const int hh = (col & 1023) >> 6, dd = col & 63;
            const int rbase = bm + wm * 128 + mf * 32 + hi * 4;
            if (which == 2) {
#pragma unroll
                for (int g = 0; g < 4; ++g) {
                    const int rb = rbase + g * 8;
                    const int b = rb >> 11, tq = rb & 2047;
                    h4 pv;
#pragma unroll
                    for (int i = 0; i < 4; ++i) pv[i] = (_Float16)(acc[mf][nf][g * 4 + i] + bv);
                    *(h4*)(oV + ((size_t)(b * 16 + hh) * 64 + dd) * 2048 + tq) = pv;
                }
            } else {
                _Float16* dst = which == 0 ? oQ : oK;
                const float scl = which == 0 ? 0.18033688011112042f : 1.0f; // 0.125*log2(e)
#pragma unroll
                for (int g = 0; g < 4; ++g)
#pragma unroll
                    for (int i = 0; i < 4; ++i) {
                        const int rb = rbase + g * 8 + i;
                        const int b = rb >> 11, tq = rb & 2047;
                        dst[(((size_t)b * 16 + hh) * 2048 + tq) * 64 + dd] =
                            (_Float16)((acc[mf][nf][g * 4 + i] + bv) * scl);
                    }
            }
        }
    }
}

// ---------------- 128x128 MFMA GEMM, 3-slot ring + counted vmcnt (proj) ----------------
__global__ __launch_bounds__(256) void k_gemm_proj(const _Float16* __restrict__ A,
                                                   const _Float16* __restrict__ Bt,
                                                   const float* __restrict__ bias,
                                                   float* __restrict__ oF,
                                                   int M, int N, int K) {
    __shared__ _Float16 As[3][128 * 32];
    __shared__ _Float16 Bs[3][128 * 32];
    const int tid = threadIdx.x;
    const int lane = tid & 63, wv = tid >> 6;
    const int wm = wv >> 1, wn = wv & 1;
    const int l15 = lane & 15, l4 = lane >> 4;
    const int bm = blockIdx.x * 128, bn = blockIdx.y * 128;
    f4 acc[4][4] = {};

    const int srow = lane >> 2, scol = (lane & 3) * 8;
    const _Float16* Ag = A + (size_t)(bm + srow) * K + scol;
    const _Float16* Bg = Bt + (size_t)(bn + srow) * K + scol;

    auto STAGE = [&](int tile, int s) {
        const size_t ko = (size_t)tile * 32;
#pragma unroll
        for (int j = 0; j < 2; ++j) {
            const int rb_ = (wv * 2 + j) * 16;
            gload16(Ag + (size_t)rb_ * K + ko, &As[s][(wv * 2 + j) * 512]);
            gload16(Bg + (size_t)rb_ * K + ko, &Bs[s][(wv * 2 + j) * 512]);
        }
    };

    const int NT = K >> 5;
    STAGE(0, 0);
    STAGE(1, 1);
    asm volatile("s_waitcnt vmcnt(4)" ::: "memory");
    __builtin_amdgcn_s_barrier();

    int cs = 0;
    for (int t = 0; t < NT; ++t) {
        const int s2 = cs + 2 >= 3 ? cs - 1 : cs + 2;
        const bool pre2 = (t + 2 < NT);
        if (pre2) STAGE(t + 2, s2);

        const _Float16* Ac = As[cs];
        const _Float16* Bc = Bs[cs];
        h8 af[4], bf[4];
#pragma unroll
        for (int i = 0; i < 4; ++i)
            af[i] = *(const h8*)(&Ac[(wm * 64 + i * 16 + l15) * 32 + l4 * 8]);
#pragma unroll
        for (int i = 0; i < 4; ++i)
            bf[i] = *(const h8*)(&Bc[(wn * 64 + i * 16 + l15) * 32 + l4 * 8]);
        __builtin_amdgcn_s_setprio(1);
#pragma unroll
        for (int mi = 0; mi < 4; ++mi)
#pragma unroll
            for (int ni = 0; ni < 4; ++ni)
                acc[mi][ni] = MFMA16(af[mi], bf[ni], acc[mi][ni]);
        __builtin_amdgcn_s_setprio(0);

        if (t + 1 < NT) {
            if (pre2) asm volatile("s_waitcnt vmcnt(4)" ::: "memory");
            else      asm volatile("s_waitcnt vmcnt(0)" ::: "memory");
            __builtin_amdgcn_s_barrier();
        }
        cs = cs + 1 == 3 ? 0 : cs + 1;
    }

#pragma unroll
    for (int mi = 0; mi < 4; ++mi) {
#pragma unroll
        for (int ni = 0; ni < 4; ++ni) {
            int col = bn + wn * 64 + ni * 16 + l15;
            float bv = bias[col];
            int rb = bm + wm * 64 + mi * 16 + l4 * 4;
#pragma unroll
            for (int i = 0; i < 4; ++i)
                oF[(size_t)(rb + i) * N + col] = acc[mi][ni][i] + bv;
        }
    }
}

// ---------------- causal flash attention: 4 waves x 32 q-rows, shared 64-key K/V tile ----------------
#define SWZI(row, cb) ((((row) << 7) + ((cb) ^ ((((row) & 7) << 4)))) >> 1)

__global__ __launch_bounds__(256) void k_attn(const _Float16* __restrict__ Qh,
                                              const _Float16* __restrict__ Kh,
                                              const _Float16* __restrict__ Vt,
                                              _Float16* __restrict__ Yh) {
    __shared__ _Float16 lds[8192];
    const int bid = blockIdx.x;
    const int bh = bid & 63;
    const int qt = 15 - (bid >> 6);
    const int tid = threadIdx.x, w = tid >> 6;
    const int l31 = tid & 31, hi = (tid >> 5) & 1;
    const int h16 = hi * 16, h4o = hi * 4;
    const size_t base = (size_t)bh * 2048 * 64;

    const int qabs = qt * 128 + w * 32 + l31;
    h8 qf[4];
#pragma unroll
    for (int dk = 0; dk < 4; ++dk)
        qf[dk] = *(const h8*)(Qh + base + (size_t)qabs * 64 + dk * 16 + hi * 8);

    f16x O0 = {}, O1 = {};
    float m = -1e30f, l = 0.f;

    const int sr = tid >> 3;
    const int sc8 = (tid & 7) * 8;
    const int scb = (tid & 7) * 16;
    const int kbb = 2 * qt + 1;
    const int kbw = 2 * qt + (w >> 1);

    {
#pragma unroll
        for (int j = 0; j < 2; ++j) {
            int row = j * 32 + sr;
            h8 kv = *(const h8*)(Kh + base + (size_t)row * 64 + sc8);
            h8 vv = *(const h8*)(Vt + base + (size_t)row * 2048 + sc8);
            *(h8*)(&lds[SWZI(row, scb)]) = kv;
            *(h8*)(&lds[4096 + SWZI(row, scb)]) = vv;
        }
    }
    __syncthreads();

    for (int kb = 0; kb <= kbb; ++kb) {
        const bool pre = (kb < kbb);
        h8 kn[2], vn[2];
        if (pre) {
#pragma unroll
            for (int j = 0; j < 2; ++j) {
                int row = j * 32 + sr;
                kn[j] = *(const h8*)(Kh + base + (size_t)((kb + 1) * 64 + row) * 64 + sc8);
                vn[j] = *(const h8*)(Vt + base + (size_t)row * 2048 + (kb + 1) * 64 + sc8);
            }
        }

        if (kb <= kbw) {
            f16x S0 = {}, S1 = {};
            __builtin_amdgcn_s_setprio(1);
#pragma unroll
            for (int dk = 0; dk < 4; ++dk) {
                h8 kf0 = *(const h8*)(&lds[SWZI(l31, dk * 32 + h16)]);
                h8 kf1 = *(const h8*)(&lds[SWZI(32 + l31, dk * 32 + h16)]);
                S0 = MFMA32(kf0, qf[dk], S0);
                S1 = MFMA32(kf1, qf[dk], S1);
            }
            __builtin_amdgcn_s_setprio(0);

            if (kb == kbw) {
#pragma unroll
                for (int r = 0; r < 16; ++r) {
                    int key = kb * 64 + (r & 3) + 8 * (r >> 2) + h4o;
                    if (key > qabs) S0[r] = -1e30f;
                    if (key + 32 > qabs) S1[r] = -1e30f;
                }
            }

            float tr[16];
#pragma unroll
            for (int r = 0; r < 16; ++r) tr[r] = fmaxf(S0[r], S1[r]);
#pragma unroll
            for (int st = 8; st >= 1; st >>= 1)
#pragma unroll
                for (int r = 0; r < st; ++r) tr[r] = fmaxf(tr[r], tr[r + st]);
            float pm = fmaxf(tr[0], swap_half(tr[0]));
            if (!__all(pm - m <= 8.f)) {
                float mnew = fmaxf(m, pm);
                float scl = __builtin_amdgcn_exp2f(m - mnew);
                m = mnew;
                l *= scl;
#pragma unroll
                for (int r = 0; r < 16; ++r) { O0[r] *= scl; O1[r] *= scl; }
            }
#pragma unroll
            for (int r = 0; r < 16; ++r) {
                S0[r] = __builtin_amdgcn_exp2f(S0[r] - m);
                S1[r] = __builtin_amdgcn_exp2f(S1[r] - m);
            }
#pragma unroll
            for (int r = 0; r < 16; ++r) tr[r] = S0[r] + S1[r];
#pragma unroll
            for (int st = 8; st >= 1; st >>= 1)
#pragma unroll
                for (int r = 0; r < st; ++r) tr[r] += tr[r + st];
            l += tr[0] + swap_half(tr[0]);

            h8 pb[4];
#pragma unroll
            for (int kk = 0; kk < 4; ++kk) {
                const int bb = (kk & 1) * 8;
                unsigned W0, W1, W2, W3;
                if (kk < 2) {
                    W0 = __builtin_bit_cast(unsigned, __builtin_amdgcn_cvt_pkrtz(S0[bb + 0], S0[bb + 1]));
                    W1 = __builtin_bit_cast(unsigned, __builtin_amdgcn_cvt_pkrtz(S0[bb + 2], S0[bb + 3]));
                    W2 = __builtin_bit_cast(unsigned, __builtin_amdgcn_cvt_pkrtz(S0[bb + 4], S0[bb + 5]));
                    W3 = __builtin_bit_cast(unsigned, __builtin_amdgcn_cvt_pkrtz(S0[bb + 6], S0[bb + 7]));
                } else {
                    W0 = __builtin_bit_cast(unsigned, __builtin_amdgcn_cvt_pkrtz(S1[bb + 0], S1[bb + 1]));
                    W1 = __builtin_bit_cast(unsigned, __builtin_amdgcn_cvt_pkrtz(S1[bb + 2], S1[bb + 3]));
                    W2 = __builtin_bit_cast(unsigned, __builtin_amdgcn_cvt_pkrtz(S1[bb + 4], S1[bb + 5]));
                    W3 = __builtin_bit_cast(unsigned, __builtin_amdgcn_cvt_pkrtz(S1[bb + 6], S1[bb + 7]));
                }
                unsigned E0 = (unsigned)__shfl_xor((int)(hi ? W0 : W2), 32, 64);
                unsigned E1 = (unsigned)__shfl_xor((int)(hi ? W1 : W3), 32, 64);
                u4 wvv;
                wvv[0] = hi ? E0 : W0;
                wvv[1] = hi ? E1 : W1;
                wvv[2] = hi ? W2 : E0;
                wvv[3] = hi ? W3 : E1;
                pb[kk] = __builtin_bit_cast(h8, wvv);
            }

            __builtin_amdgcn_s_setprio(1);
#pragma unroll
            for (int kk = 0; kk < 4; ++kk) {
                h8 vf0 = *(const h8*)(&lds[4096 + SWZI(l31, kk * 32 + h16)]);
                h8 vf1 = *(const h8*)(&lds[4096 + SWZI(32 + l31, kk * 32 + h16)]);
                O0 = MFMA32(vf0, pb[kk], O0);
                O1 = MFMA32(vf1, pb[kk], O1);
            }
            __builtin_amdgcn_s_setprio(0);
        }

        __syncthreads();
        if (pre) {
#pragma unroll
            for (int j = 0; j < 2; ++j) {
                int row = j * 32 + sr;
                *(h8*)(&lds[SWZI(row, scb)]) = kn[j];
                *(h8*)(&lds[4096 + SWZI(row, scb)]) = vn[j];
            }
            __syncthreads();
        }
    }

    __syncthreads();

    {
        float inv = 1.0f / l;
        const int R = w * 32 + l31;
#pragma unroll
        for (int rr = 0; rr < 4; ++rr) {
            h4 a, b;
#pragma unroll
            for (int q = 0; q < 4; ++q) {
                a[q] = (_Float16)(O0[rr * 4 + q] * inv);
                b[q] = (_Float16)(O1[rr * 4 + q] * inv);
            }
            *(h4*)(&lds[SWZI(R, rr * 16 + hi * 8)]) = a;
            *(h4*)(&lds[SWZI(R, 64 + rr * 16 + hi * 8)]) = b;
        }
    }
    __syncthreads();
    {
        const int b = bh >> 4, head = bh & 15;
        const int row = tid >> 1;
#pragma unroll
        for (int i = 0; i < 4; ++i) {
            int seg = (tid & 1) * 4 + i;
            h8 v = *(const h8*)(&lds[SWZI(row, seg * 16)]);
            *(h8*)(Yh + ((size_t)(b * 2048 + qt * 128 + row)) * 1024 + head * 64 + seg * 8) = v;
        }
    }
}

extern "C" void kernel_launch(void* const* d_in, const int* in_sizes, int n_in,
                              void* d_out, int out_size, void* d_ws, size_t ws_size,
                              hipStream_t stream) {
    const float* x  = (const float*)d_in[0];
    const float* Wa = (const float*)d_in[1];
    const float* ba = (const float*)d_in[2];
    const float* Wp = (const float*)d_in[3];
    const float* bp = (const float*)d_in[4];
    float* out = (float*)d_out;

    _Float16* ws = (_Float16*)d_ws;
    const size_t SZ_X = (size_t)8192 * 1024;
    const size_t SZ_WA = (size_t)3072 * 1024;
    const size_t SZ_WP = (size_t)1024 * 1024;
    const size_t SZ_H = (size_t)64 * 2048 * 64;
    _Float16* xh  = ws;
    _Float16* WaT = xh + SZ_X;
    _Float16* WpT = WaT + SZ_WA;
    _Float16* Qh  = WpT + SZ_WP;
    _Float16* Kh  = Qh + SZ_H;
    _Float16* Vth = Kh + SZ_H;    // V transposed: (bh, d, t)
    _Float16* Yh  = Vth + SZ_H;

    k_f32_to_f16<<<8192, 256, 0, stream>>>(x, xh, (int)(SZ_X / 4));
    k_transpose_f16<<<dim3(16, 48), 256, 0, stream>>>(Wa, WaT, 1024, 3072);
    k_transpose_f16<<<dim3(16, 16), 256, 0, stream>>>(Wp, WpT, 1024, 1024);
    k_gemm256<<<384, 512, 0, stream>>>(xh, WaT, ba, Qh, Kh, Vth, 1024, 12);
    k_attn<<<1024, 256, 0, stream>>>(Qh, Kh, Vth, Yh);
    k_gemm_proj<<<dim3(64, 8), 256, 0, stream>>>(Yh, WpT, bp, out, 8192, 1024, 1024);
}

// Round 11
// 181.852 us; speedup vs baseline: 1.0382x; 1.0382x over previous
//
#include <hip/hip_runtime.h>

typedef __attribute__((ext_vector_type(8))) _Float16 h8;
typedef __attribute__((ext_vector_type(4))) _Float16 h4;
typedef __attribute__((ext_vector_type(4))) float f4;
typedef __attribute__((ext_vector_type(16))) float f16x;
typedef __attribute__((ext_vector_type(4))) unsigned u4;

#define MFMA16(a,b,c) __builtin_amdgcn_mfma_f32_16x16x32_f16(a,b,c,0,0,0)
#define MFMA32(a,b,c) __builtin_amdgcn_mfma_f32_32x32x16_f16(a,b,c,0,0,0)

// async global->LDS, 16B per lane; LDS dest = wave-uniform base + lane*16
__device__ inline void gload16(const void* g, void* l) {
    __builtin_amdgcn_global_load_lds(
        (const __attribute__((address_space(1))) void*)g,
        (__attribute__((address_space(3))) void*)l, 16, 0, 0);
}

// partner-half (lane ^ 32) value, semantics-guaranteed
__device__ inline float swap_half(float x) { return __shfl_xor(x, 32, 64); }

// ---------------- fp32 -> f16 elementwise (vectorized) ----------------
__global__ __launch_bounds__(256) void k_f32_to_f16(const float* __restrict__ in,
                                                    _Float16* __restrict__ out, int n4) {
    int i = blockIdx.x * 256 + threadIdx.x;
    if (i < n4) {
        float4 v = ((const float4*)in)[i];
        h4 h;
        h[0] = (_Float16)v.x; h[1] = (_Float16)v.y;
        h[2] = (_Float16)v.z; h[3] = (_Float16)v.w;
        ((h4*)out)[i] = h;
    }
}

// ---------------- fp32 (K,N) -> f16 (N,K) tiled transpose ----------------
__global__ __launch_bounds__(256) void k_transpose_f16(const float* __restrict__ W,
                                                       _Float16* __restrict__ Wt,
                                                       int K, int N) {
    __shared__ float tile[64 * 68];
    const int k0 = blockIdx.x * 64, n0 = blockIdx.y * 64;
    const int t = threadIdx.x;
    const int tr = t >> 4;
    const int tc = t & 15;
#pragma unroll
    for (int i = 0; i < 4; ++i) {
        int r = tr + i * 16;
        float4 v = *(const float4*)(W + (size_t)(k0 + r) * N + n0 + tc * 4);
        *(float4*)(&tile[r * 68 + tc * 4]) = v;
    }
    __syncthreads();
#pragma unroll
    for (int i = 0; i < 4; ++i) {
        int nl = tr + i * 16;
        h4 hv;
#pragma unroll
        for (int j = 0; j < 4; ++j)
            hv[j] = (_Float16)tile[(tc * 4 + j) * 68 + nl];
        *(h4*)(Wt + (size_t)(n0 + nl) * K + k0 + tc * 4) = hv;
    }
}

// ======== 256xBN fine-interleaved 4-phase GEMM: 8 waves (2Mx4N), 16x16x32 MFMA ========
// BK=64, 2 LDS slots. Phase q of tile tau: {frag ds_reads | stage chunk q of tau+1
// into slot s^1 | (q3) vmcnt(0) | raw barrier | setprio + 2xNFx2 MFMA + setprio |
// raw barrier}. Last-staged chunk gets >=1 full MFMA phase of latency cover; slot
// flip is race-free via lgkmcnt-before-MFMA + trailing barrier.
// T2: LDS (row, seg) holds global seg (seg ^ (row&7)); applied on per-lane stage
// SOURCE col and on frag-read seg (involution). Verified in r10 (passed).
// MODE 0: scatter Q/K (B,H,T,64), V^T (B,H,64,T); Q pre-scaled 0.125*log2(e).
// MODE 1: f32 out.
template <int BN, int MODE>
__global__ __launch_bounds__(512, 2) void k_gemm2(const _Float16* __restrict__ A,
                                                  const _Float16* __restrict__ Bt,
                                                  const float* __restrict__ bias,
                                                  _Float16* __restrict__ oQ,
                                                  _Float16* __restrict__ oK,
                                                  _Float16* __restrict__ oV,
                                                  float* __restrict__ oF,
                                                  int K, int N, int nbn) {
    constexpr int NF = BN / 64;            // B frags per wave == B stage rounds
    __shared__ _Float16 As[2][256 * 64];
    __shared__ _Float16 Bs[2][BN * 64];
    const int nwg = gridDim.x;
    const int q8 = nwg >> 3;               // nwg % 8 == 0
    const int wg = (blockIdx.x & 7) * q8 + (blockIdx.x >> 3);   // XCD-chunked, bijective
    const int bm = (wg / nbn) * 256, bn = (wg % nbn) * BN;
    const int tid = threadIdx.x, lane = tid & 63, wv = tid >> 6;
    const int wm = wv >> 2, wn = wv & 3;   // per-wave out: 128 x (BN/4)
    const int l15 = lane & 15, l4 = lane >> 4;
    const int sr8 = lane >> 3;             // stage row-in-octet
    const int sseg = ((lane & 7) ^ sr8) * 8;   // T2 pre-swizzled source col
    const _Float16* Ag = A + (size_t)(bm + wv * 8 + sr8) * K + sseg;
    const _Float16* Bg = Bt + (size_t)(bn + wv * 8 + sr8) * K + sseg;
    f4 acc[8][NF] = {};

    const int NT = K >> 6;

    // prologue: stage tile 0 -> slot 0
#pragma unroll
    for (int j = 0; j < 4; ++j) gload16(Ag + (size_t)j * 64 * K, &As[0][(j * 64 + wv * 8) * 64]);
#pragma unroll
    for (int j = 0; j < NF; ++j) gload16(Bg + (size_t)j * 64 * K, &Bs[0][(j * 64 + wv * 8) * 64]);
    asm volatile("s_waitcnt vmcnt(0)" ::: "memory");
    __builtin_amdgcn_s_barrier();

    for (int tau = 0; tau < NT; ++tau) {
        const int s = tau & 1;
        const bool pre = (tau + 1 < NT);
        const size_t ko = (size_t)(tau + 1) << 6;

        // B-frags for this tile (persist across phases)
        h8 bf[NF][2];
#pragma unroll
        for (int nf = 0; nf < NF; ++nf)
#pragma unroll
            for (int ks = 0; ks < 2; ++ks) {
                const int row = wn * (BN / 4) + nf * 16 + l15;
                const int seg = (ks * 4 + l4) ^ (l15 & 7);
                bf[nf][ks] = *(const h8*)(&Bs[s][row * 64 + seg * 8]);
            }

#pragma unroll
        for (int q = 0; q < 4; ++q) {
            h8 af[2][2];
#pragma unroll
            for (int mi = 0; mi < 2; ++mi)
#pragma unroll
                for (int ks = 0; ks < 2; ++ks) {
                    const int row = wm * 128 + (2 * q + mi) * 16 + l15;
                    const int seg = (ks * 4 + l4) ^ (l15 & 7);
                    af[mi][ks] = *(const h8*)(&As[s][row * 64 + seg * 8]);
                }
            if (pre) {
                if (q == 0) {
                    gload16(Ag + ko, &As[s ^ 1][(wv * 8) * 64]);
                    gload16(Ag + (size_t)64 * K + ko, &As[s ^ 1][(64 + wv * 8) * 64]);
                } else if (q == 1) {
                    gload16(Ag + (size_t)128 * K + ko, &As[s ^ 1][(128 + wv * 8) * 64]);
                    gload16(Ag + (size_t)192 * K + ko, &As[s ^ 1][(192 + wv * 8) * 64]);
                } else if (q == 2) {
#pragma unroll
                    for (int j = 0; j < NF; ++j)
                        gload16(Bg + (size_t)j * 64 * K + ko, &Bs[s ^ 1][(j * 64 + wv * 8) * 64]);
                } else {
                    asm volatile("s_waitcnt vmcnt(0)" ::: "memory");  // tile tau+1 resident
                }
            }
            __builtin_amdgcn_s_barrier();
            __builtin_amdgcn_s_setprio(1);
#pragma unroll
            for (int mi = 0; mi < 2; ++mi)
#pragma unroll
                for (int nf = 0; nf < NF; ++nf)
#pragma unroll
                    for (int ks = 0; ks < 2; ++ks)
                        acc[2 * q + mi][nf] = MFMA16(af[mi][ks], bf[nf][ks], acc[2 * q + mi][nf]);
            __builtin_amdgcn_s_setprio(0);
            __builtin_amdgcn_s_barrier();
        }
    }

    // epilogue
#pragma unroll
    for (int mf = 0; mf < 8; ++mf) {
#pragma unroll
        for (int nf = 0; nf < NF; ++nf) {
            const int col = bn + wn * (BN / 4) + nf * 16 + l15;
            const float bv = bias[col];
            const int rb = bm + wm * 128 + mf * 16 + l4 * 4;
            if (MODE == 0) {
                const int which = col >> 10;         // col blocks of 16 never straddle 1024
                const int hh = (col & 1023) >> 6, dd = col & 63;
                if (which == 2) {
                    const int b = rb >> 11, tq = rb & 2047;
                    h4 pv;
#pragma unroll
                    for (int i = 0; i < 4; ++i) pv[i] = (_Float16)(acc[mf][nf][i] + bv);
                    *(h4*)(oV + ((size_t)(b * 16 + hh) * 64 + dd) * 2048 + tq) = pv;
                } else {
                    _Float16* dst = which == 0 ? oQ : oK;
                    const float scl = which == 0 ? 0.18033688011112042f : 1.0f; // 0.125*log2(e)
#pragma unroll
                    for (int i = 0; i < 4; ++i) {
                        const int row = rb + i;
                        const int b = row >> 11, tq = row & 2047;
                        dst[(((size_t)b * 16 + hh) * 2048 + tq) * 64 + dd] =
                            (_Float16)((acc[mf][nf][i] + bv) * scl);
                    }
                }
            } else {
#pragma unroll
                for (int i = 0; i < 4; ++i)
                    oF[(size_t)(rb + i) * N + col] = acc[mf][nf][i] + bv;
            }
        }
    }
}

// ---------------- causal flash attention: 4 waves x 32 q-rows, shared 64-key K/V tile ----------------
#define SWZI(row, cb) ((((row) << 7) + ((cb) ^ ((((row) & 7) << 4)))) >> 1)

__global__ __launch_bounds__(256) void k_attn(const _Float16* __restrict__ Qh,
                                              const _Float16* __restrict__ Kh,
                                              const _Float16* __restrict__ Vt,
                                              _Float16* __restrict__ Yh) {
    __shared__ _Float16 lds[8192];
    const int bid = blockIdx.x;
    const int bh = bid & 63;
    const int qt = 15 - (bid >> 6);
    const int tid = threadIdx.x, w = tid >> 6;
    const int l31 = tid & 31, hi = (tid >> 5) & 1;
    const int h16 = hi * 16, h4o = hi * 4;
    const size_t base = (size_t)bh * 2048 * 64;

    const int qabs = qt * 128 + w * 32 + l31;
    h8 qf[4];
#pragma unroll
    for (int dk = 0; dk < 4; ++dk)
        qf[dk] = *(const h8*)(Qh + base + (size_t)qabs * 64 + dk * 16 + hi * 8);

    f16x O0 = {}, O1 = {};
    float m = -1e30f, l = 0.f;

    const int sr = tid >> 3;
    const int sc8 = (tid & 7) * 8;
    const int scb = (tid & 7) * 16;
    const int kbb = 2 * qt + 1;
    const int kbw = 2 * qt + (w >> 1);

    {
#pragma unroll
        for (int j = 0; j < 2; ++j) {
            int row = j * 32 + sr;
            h8 kv = *(const h8*)(Kh + base + (size_t)row * 64 + sc8);
            h8 vv = *(const h8*)(Vt + base + (size_t)row * 2048 + sc8);
            *(h8*)(&lds[SWZI(row, scb)]) = kv;
            *(h8*)(&lds[4096 + SWZI(row, scb)]) = vv;
        }
    }
    __syncthreads();

    for (int kb = 0; kb <= kbb; ++kb) {
        const bool pre = (kb < kbb);
        h8 kn[2], vn[2];
        if (pre) {
#pragma unroll
            for (int j = 0; j < 2; ++j) {
                int row = j * 32 + sr;
                kn[j] = *(const h8*)(Kh + base + (size_t)((kb + 1) * 64 + row) * 64 + sc8);
                vn[j] = *(const h8*)(Vt + base + (size_t)row * 2048 + (kb + 1) * 64 + sc8);
            }
        }

        if (kb <= kbw) {
            f16x S0 = {}, S1 = {};
            __builtin_amdgcn_s_setprio(1);
#pragma unroll
            for (int dk = 0; dk < 4; ++dk) {
                h8 kf0 = *(const h8*)(&lds[SWZI(l31, dk * 32 + h16)]);
                h8 kf1 = *(const h8*)(&lds[SWZI(32 + l31, dk * 32 + h16)]);
                S0 = MFMA32(kf0, qf[dk], S0);
                S1 = MFMA32(kf1, qf[dk], S1);
            }
            __builtin_amdgcn_s_setprio(0);

            if (kb == kbw) {
#pragma unroll
                for (int r = 0; r < 16; ++r) {
                    int key = kb * 64 + (r & 3) + 8 * (r >> 2) + h4o;
                    if (key > qabs) S0[r] = -1e30f;
                    if (key + 32 > qabs) S1[r] = -1e30f;
                }
            }

            float tr[16];
#pragma unroll
            for (int r = 0; r < 16; ++r) tr[r] = fmaxf(S0[r], S1[r]);
#pragma unroll
            for (int st = 8; st >= 1; st >>= 1)
#pragma unroll
                for (int r = 0; r < st; ++r) tr[r] = fmaxf(tr[r], tr[r + st]);
            float pm = fmaxf(tr[0], swap_half(tr[0]));
            if (!__all(pm - m <= 8.f)) {
                float mnew = fmaxf(m, pm);
                float scl = __builtin_amdgcn_exp2f(m - mnew);
                m = mnew;
                l *= scl;
#pragma unroll
                for (int r = 0; r < 16; ++r) { O0[r] *= scl; O1[r] *= scl; }
            }
#pragma unroll
            for (int r = 0; r < 16; ++r) {
                S0[r] = __builtin_amdgcn_exp2f(S0[r] - m);
                S1[r] = __builtin_amdgcn_exp2f(S1[r] - m);
            }
#pragma unroll
            for (int r = 0; r < 16; ++r) tr[r] = S0[r] + S1[r];
#pragma unroll
            for (int st = 8; st >= 1; st >>= 1)
#pragma unroll
                for (int r = 0; r < st; ++r) tr[r] += tr[r + st];
            l += tr[0] + swap_half(tr[0]);

            h8 pb[4];
#pragma unroll
            for (int kk = 0; kk < 4; ++kk) {
                const int bb = (kk & 1) * 8;
                unsigned W0, W1, W2, W3;
                if (kk < 2) {
                    W0 = __builtin_bit_cast(unsigned, __builtin_amdgcn_cvt_pkrtz(S0[bb + 0], S0[bb + 1]));
                    W1 = __builtin_bit_cast(unsigned, __builtin_amdgcn_cvt_pkrtz(S0[bb + 2], S0[bb + 3]));
                    W2 = __builtin_bit_cast(unsigned, __builtin_amdgcn_cvt_pkrtz(S0[bb + 4], S0[bb + 5]));
                    W3 = __builtin_bit_cast(unsigned, __builtin_amdgcn_cvt_pkrtz(S0[bb + 6], S0[bb + 7]));
                } else {
                    W0 = __builtin_bit_cast(unsigned, __builtin_amdgcn_cvt_pkrtz(S1[bb + 0], S1[bb + 1]));
                    W1 = __builtin_bit_cast(unsigned, __builtin_amdgcn_cvt_pkrtz(S1[bb + 2], S1[bb + 3]));
                    W2 = __builtin_bit_cast(unsigned, __builtin_amdgcn_cvt_pkrtz(S1[bb + 4], S1[bb + 5]));
                    W3 = __builtin_bit_cast(unsigned, __builtin_amdgcn_cvt_pkrtz(S1[bb + 6], S1[bb + 7]));
                }
                unsigned E0 = (unsigned)__shfl_xor((int)(hi ? W0 : W2), 32, 64);
                unsigned E1 = (unsigned)__shfl_xor((int)(hi ? W1 : W3), 32, 64);
                u4 wvv;
                wvv[0] = hi ? E0 : W0;
                wvv[1] = hi ? E1 : W1;
                wvv[2] = hi ? W2 : E0;
                wvv[3] = hi ? W3 : E1;
                pb[kk] = __builtin_bit_cast(h8, wvv);
            }

            __builtin_amdgcn_s_setprio(1);
#pragma unroll
            for (int kk = 0; kk < 4; ++kk) {
                h8 vf0 = *(const h8*)(&lds[4096 + SWZI(l31, kk * 32 + h16)]);
                h8 vf1 = *(const h8*)(&lds[4096 + SWZI(32 + l31, kk * 32 + h16)]);
                O0 = MFMA32(vf0, pb[kk], O0);
                O1 = MFMA32(vf1, pb[kk], O1);
            }
            __builtin_amdgcn_s_setprio(0);
        }

        __syncthreads();
        if (pre) {
#pragma unroll
            for (int j = 0; j < 2; ++j) {
                int row = j * 32 + sr;
                *(h8*)(&lds[SWZI(row, scb)]) = kn[j];
                *(h8*)(&lds[4096 + SWZI(row, scb)]) = vn[j];
            }
            __syncthreads();
        }
    }

    __syncthreads();

    {
        float inv = 1.0f / l;
        const int R = w * 32 + l31;
#pragma unroll
        for (int rr = 0; rr < 4; ++rr) {
            h4 a, b;
#pragma unroll
            for (int q = 0; q < 4; ++q) {
                a[q] = (_Float16)(O0[rr * 4 + q] * inv);
                b[q] = (_Float16)(O1[rr * 4 + q] * inv);
            }
            *(h4*)(&lds[SWZI(R, rr * 16 + hi * 8)]) = a;
            *(h4*)(&lds[SWZI(R, 64 + rr * 16 + hi * 8)]) = b;
        }
    }
    __syncthreads();
    {
        const int b = bh >> 4, head = bh & 15;
        const int row = tid >> 1;
#pragma unroll
        for (int i = 0; i < 4; ++i) {
            int seg = (tid & 1) * 4 + i;
            h8 v = *(const h8*)(&lds[SWZI(row, seg * 16)]);
            *(h8*)(Yh + ((size_t)(b * 2048 + qt * 128 + row)) * 1024 + head * 64 + seg * 8) = v;
        }
    }
}

extern "C" void kernel_launch(void* const* d_in, const int* in_sizes, int n_in,
                              void* d_out, int out_size, void* d_ws, size_t ws_size,
                              hipStream_t stream) {
    const float* x  = (const float*)d_in[0];
    const float* Wa = (const float*)d_in[1];
    const float* ba = (const float*)d_in[2];
    const float* Wp = (const float*)d_in[3];
    const float* bp = (const float*)d_in[4];
    float* out = (float*)d_out;

    _Float16* ws = (_Float16*)d_ws;
    const size_t SZ_X = (size_t)8192 * 1024;
    const size_t SZ_WA = (size_t)3072 * 1024;
    const size_t SZ_WP = (size_t)1024 * 1024;
    const size_t SZ_H = (size_t)64 * 2048 * 64;
    _Float16* xh  = ws;
    _Float16* WaT = xh + SZ_X;
    _Float16* WpT = WaT + SZ_WA;
    _Float16* Qh  = WpT + SZ_WP;
    _Float16* Kh  = Qh + SZ_H;
    _Float16* Vth = Kh + SZ_H;    // V transposed: (bh, d, t)
    _Float16* Yh  = Vth + SZ_H;

    k_f32_to_f16<<<8192, 256, 0, stream>>>(x, xh, (int)(SZ_X / 4));
    k_transpose_f16<<<dim3(16, 48), 256, 0, stream>>>(Wa, WaT, 1024, 3072);
    k_transpose_f16<<<dim3(16, 16), 256, 0, stream>>>(Wp, WpT, 1024, 1024);
    // QKV: 256x192 tiles -> grid 32*16 = 512 = exactly 2 rounds of 256 CUs
    k_gemm2<192, 0><<<512, 512, 0, stream>>>(xh, WaT, ba, Qh, Kh, Vth, nullptr,
                                             1024, 3072, 16);
    k_attn<<<1024, 256, 0, stream>>>(Qh, Kh, Vth, Yh);
    // proj: 256x128 tiles -> grid 32*8 = 256 = exactly 1 round
    k_gemm2<128, 1><<<256, 512, 0, stream>>>(Yh, WpT, bp, nullptr, nullptr, nullptr,
                                             out, 1024, 1024, 8);
}